// Round 1
// baseline (238.133 us; speedup 1.0000x reference)
//
#include <hip/hip_runtime.h>

// CompoundClassifier: per-edge 2-layer MLP with feature gather.
//   src = x_ing[eidx[0][e]] (128 f32), dst = x_cmp[eidx[1][e]]
//   h = relu([src,dst] @ W1 + b1)   [E,256]@[256,128]
//   out = sigmoid(h @ W2 + b2)      [E,128]@[128,1]
// Strategy: f16 MFMA gather-GEMM (M=1M, N=128, K=256), layer 2 fused in epilogue.

#define H       128
#define NI      20000
#define NC      10000
#define NE      1000000
#define MT      64                  // edges per tile
#define NTILES  (NE / MT)           // 15625 (exact)
#define GRID    3125                // 15625 / 3125 = 5 tiles per block, perfectly balanced

typedef _Float16 half8  __attribute__((ext_vector_type(8)));
typedef _Float16 half4v __attribute__((ext_vector_type(4)));
typedef float    floatx4 __attribute__((ext_vector_type(4)));

// d_ws layout in _Float16 elements:
//   [0, NI*H)            x_ingredient as f16
//   [NI*H, NI*H+NC*H)    x_compound as f16
//   [W1T_OFF, +128*256)  W1 transposed: [n][k] (contiguous k for B-fragments)
#define XIN_OFF  0
#define XCMP_OFF (NI * H)
#define W1T_OFF  (NI * H + NC * H)

__global__ void cvt_features(const float* __restrict__ xin,
                             const float* __restrict__ xcmp,
                             _Float16* __restrict__ ws) {
    long i = ((long)blockIdx.x * 256 + threadIdx.x) * 4;   // element index, 4 per thread
    float4 v;
    if (i < (long)NI * H) v = *(const float4*)(xin + i);
    else                  v = *(const float4*)(xcmp + (i - (long)NI * H));
    half4v h = { (_Float16)v.x, (_Float16)v.y, (_Float16)v.z, (_Float16)v.w };
    *(half4v*)(ws + i) = h;
}

__global__ void cvt_w1(const float* __restrict__ W1, _Float16* __restrict__ ws) {
    int i = blockIdx.x * 256 + threadIdx.x;   // over 128*256
    int n = i >> 8, k = i & 255;
    ws[W1T_OFF + i] = (_Float16)W1[k * H + n];   // W1 is [256][128] row-major
}

__launch_bounds__(256, 2)
__global__ void edge_mlp(const _Float16* __restrict__ ws,
                         const int* __restrict__ src_idx,
                         const int* __restrict__ dst_idx,
                         const float* __restrict__ b1,
                         const float* __restrict__ W2,
                         const float* __restrict__ b2p,
                         float* __restrict__ out) {
    // A tile: 64 edges x 256 k, f16, XOR-swizzled 16B chunks (32 chunks/row).
    // stored_chunk = logical_chunk ^ (edge & 7)  -> both ds_write_b128 (staging)
    // and ds_read_b128 (A-frags) land at 2-way bank aliasing = free.
    __shared__ _Float16 Alds[MT * 256];       // 32 KB
    __shared__ float red[4 * MT];             // cross-wave layer-2 partials

    const int tid  = threadIdx.x;
    const int lane = tid & 63;
    const int w    = tid >> 6;      // wave 0..3
    const int quad = lane >> 4;     // 0..3
    const int m    = lane & 15;     // A row / B col within 16-tile

    const _Float16* xin_h  = ws + XIN_OFF;
    const _Float16* xcmp_h = ws + XCMP_OFF;
    const _Float16* w1t    = ws + W1T_OFF;

    // ---- per-block setup: W1 B-fragments in registers (wave w owns cols w*32..w*32+31)
    half8 bfrag[2][8];
    float b1v[2], w2v[2];
#pragma unroll
    for (int t = 0; t < 2; ++t) {
        int n = w * 32 + t * 16 + m;
#pragma unroll
        for (int ks = 0; ks < 8; ++ks)
            bfrag[t][ks] = *(const half8*)(w1t + n * 256 + ks * 32 + quad * 8);
        b1v[t] = b1[n];
        w2v[t] = W2[n];   // W2 is [128][1]
    }
    const float b2v = b2p[0];

    // staging role: thread -> (edge, quarter of 256 k)
    const int se   = tid >> 2;      // edge 0..63
    const int sq   = tid & 3;       // 0,1 = src halves; 2,3 = dst halves
    const int sxor = se & 7;

    for (int tile = blockIdx.x; tile < NTILES; tile += gridDim.x) {
        const int tb = tile * MT;

        // ---- stage gathered A tile (f16) into swizzled LDS ----
        {
            int row = (sq < 2) ? src_idx[tb + se] : dst_idx[tb + se];
            const _Float16* gp = ((sq < 2) ? xin_h : xcmp_h) + (long)row * H + (sq & 1) * 64;
            _Float16* lp = Alds + se * 256;
#pragma unroll
            for (int i = 0; i < 8; ++i) {
                half8 v = *(const half8*)(gp + i * 8);
                int c = (sq * 8 + i) ^ sxor;          // swizzled chunk (stays in this quarter)
                *(half8*)(lp + c * 8) = v;
            }
        }
        __syncthreads();

        // ---- K loop: 4 m-tiles x 2 n-tiles x 8 k-steps of 16x16x32 f16 MFMA ----
        floatx4 acc[4][2];
#pragma unroll
        for (int mt = 0; mt < 4; ++mt) {
            acc[mt][0] = (floatx4)0.0f;
            acc[mt][1] = (floatx4)0.0f;
        }
#pragma unroll
        for (int mt = 0; mt < 4; ++mt) {
            const _Float16* ap = Alds + (mt * 16 + m) * 256;
            half8 afrag[8];
#pragma unroll
            for (int ks = 0; ks < 8; ++ks) {
                int c = (ks * 4 + quad) ^ (m & 7);    // un-swizzle
                afrag[ks] = *(const half8*)(ap + c * 8);
            }
#pragma unroll
            for (int t = 0; t < 2; ++t)
#pragma unroll
                for (int ks = 0; ks < 8; ++ks)
                    acc[mt][t] = __builtin_amdgcn_mfma_f32_16x16x32_f16(
                        afrag[ks], bfrag[t][ks], acc[mt][t], 0, 0, 0);
        }

        // ---- fused epilogue: relu + bias, dot with W2, reduce over 128 cols ----
        // C/D layout: col = lane&15 (n within tile), row = quad*4 + reg (edge within tile)
#pragma unroll
        for (int mt = 0; mt < 4; ++mt) {
            float p[4] = {0.f, 0.f, 0.f, 0.f};
#pragma unroll
            for (int t = 0; t < 2; ++t)
#pragma unroll
                for (int r = 0; r < 4; ++r) {
                    float v = acc[mt][t][r] + b1v[t];
                    v = fmaxf(v, 0.0f);
                    p[r] = fmaf(v, w2v[t], p[r]);
                }
            // sum over the 16 lanes of this quad (16 cols x 2 t = this wave's 32 cols)
#pragma unroll
            for (int off = 1; off < 16; off <<= 1)
#pragma unroll
                for (int r = 0; r < 4; ++r)
                    p[r] += __shfl_xor(p[r], off);
            if (m == 0) {
                float4 f; f.x = p[0]; f.y = p[1]; f.z = p[2]; f.w = p[3];
                *(float4*)(red + w * 64 + mt * 16 + quad * 4) = f;
            }
        }
        __syncthreads();   // also fences K-loop Alds reads vs next staging

        if (tid < MT) {
            float s = red[tid] + red[64 + tid] + red[128 + tid] + red[192 + tid] + b2v;
            out[tb + tid] = 1.0f / (1.0f + expf(-s));
        }
        // red readers are protected by the post-staging __syncthreads of the next tile
    }
}

extern "C" void kernel_launch(void* const* d_in, const int* in_sizes, int n_in,
                              void* d_out, int out_size, void* d_ws, size_t ws_size,
                              hipStream_t stream) {
    const float* xin  = (const float*)d_in[0];
    const float* xcmp = (const float*)d_in[1];
    const int*   eidx = (const int*)d_in[2];    // [2, E]: first E = src, next E = dst
    const float* W1   = (const float*)d_in[3];
    const float* b1   = (const float*)d_in[4];
    const float* W2   = (const float*)d_in[5];
    const float* b2   = (const float*)d_in[6];
    float* out = (float*)d_out;
    _Float16* ws = (_Float16*)d_ws;             // needs ~7.5 MB

    hipLaunchKernelGGL(cvt_features, dim3((NI + NC) * H / 4 / 256), dim3(256), 0, stream,
                       xin, xcmp, ws);
    hipLaunchKernelGGL(cvt_w1, dim3(128 * 256 / 256), dim3(256), 0, stream, W1, ws);
    hipLaunchKernelGGL(edge_mlp, dim3(GRID), dim3(256), 0, stream,
                       ws, eidx, eidx + NE, b1, W2, b2, out);
}